// Round 1
// baseline (101.870 us; speedup 1.0000x reference)
//
#include <hip/hip_runtime.h>
#include <hip/hip_bf16.h>
#include <math.h>

// S4D kernel: K[h,l] = 2 * Re( sum_n Cm[h,n] * exp(dtA[h,n] * l) )
//   dtA = dt * (-exp(log_A_real) + i*A_imag),  dt = exp(log_dt)
//   Cm  = Cc * (exp(dtA) - 1) / A
// H=1024, N/2=32, L=4096. Output (H, L) float32.

#define H_DIM 1024
#define NH 32          // N/2
#define L_DIM 4096
#define TPB 256
#define PER (L_DIM / TPB)   // 16 l-values per thread, stride TPB

__global__ __launch_bounds__(TPB) void s4d_kernel(
    const float* __restrict__ C,          // (H, NH, 2)
    const float* __restrict__ log_dt,     // (H,)
    const float* __restrict__ log_A_real, // (H, NH)
    const float* __restrict__ A_imag,     // (H, NH)
    float* __restrict__ out)              // (H, L)
{
    const int h = blockIdx.x;
    const int t = threadIdx.x;

    __shared__ float  s_cm[NH][2];  // 2*Cm (factor of 2 folded in)
    __shared__ float  s_w[NH][2];   // exp(dtA * TPB) as complex (mag folded)
    __shared__ float  s_a[NH];      // Re(dtA)
    __shared__ double s_th[NH];     // Im(dtA) reduced mod 2pi (double)

    const double TWO_PI  = 6.283185307179586476925286766559;
    const double INV_2PI = 0.15915494309189533576888376337251;

    if (t < NH) {
        const int n = t;
        const float dtf = expf(log_dt[h]);
        const float arf = -expf(log_A_real[h * NH + n]); // Re(A), negative
        const float aif = A_imag[h * NH + n];            // Im(A), >= 0
        const float are = arf * dtf;                     // Re(dtA)
        const float aim = aif * dtf;                     // Im(dtA), <= ~9.75

        // E = exp(dtA) - 1
        float m = expf(are);
        float sn, cs;
        sincosf(aim, &sn, &cs);
        const float er = m * cs - 1.0f;
        const float ei = m * sn;

        // Cm = Cc * E / A ; fold in the leading 2.0
        const float cr = C[(h * NH + n) * 2 + 0];
        const float ci = C[(h * NH + n) * 2 + 1];
        const float tr = cr * er - ci * ei;
        const float ti = cr * ei + ci * er;
        const float den = arf * arf + aif * aif;
        const float inv = 2.0f / den;
        s_cm[n][0] = (tr * arf + ti * aif) * inv;
        s_cm[n][1] = (ti * arf - tr * aif) * inv;

        s_a[n] = are;

        // phase step per l, reduced mod 2pi in double
        double th = (double)aif * (double)dtf;
        th -= floor(th * INV_2PI) * TWO_PI;
        s_th[n] = th;

        // w = exp(dtA * TPB): stride step for the l-recurrence
        const float mw = expf(are * (float)TPB);
        double pw = th * (double)TPB;
        pw -= floor(pw * INV_2PI) * TWO_PI;
        float sw, cw;
        sincosf((float)pw, &sw, &cw);
        s_w[n][0] = mw * cw;
        s_w[n][1] = mw * sw;
    }
    __syncthreads();

    float acc[PER];
#pragma unroll
    for (int j = 0; j < PER; ++j) acc[j] = 0.0f;

    for (int n = 0; n < NH; ++n) {
        const float cmr = s_cm[n][0];
        const float cmi = s_cm[n][1];
        const float wr  = s_w[n][0];
        const float wi  = s_w[n][1];
        const float a   = s_a[n];
        const double th = s_th[n];

        // z = exp(dtA * t): accurate init per thread
        const float m0 = expf(a * (float)t);
        double p0 = th * (double)t;
        p0 -= floor(p0 * INV_2PI) * TWO_PI;
        float s0, c0;
        sincosf((float)p0, &s0, &c0);
        float zr = m0 * c0;
        float zi = m0 * s0;

#pragma unroll
        for (int j = 0; j < PER; ++j) {
            acc[j] += cmr * zr - cmi * zi;   // Re(Cm * z), 2x folded in cm
            const float nzr = zr * wr - zi * wi;
            const float nzi = zr * wi + zi * wr;
            zr = nzr;
            zi = nzi;
        }
    }

    float* op = out + (size_t)h * L_DIM + t;
#pragma unroll
    for (int j = 0; j < PER; ++j) op[j * TPB] = acc[j];
}

extern "C" void kernel_launch(void* const* d_in, const int* in_sizes, int n_in,
                              void* d_out, int out_size, void* d_ws, size_t ws_size,
                              hipStream_t stream) {
    const float* C          = (const float*)d_in[0];
    const float* log_dt     = (const float*)d_in[1];
    const float* log_A_real = (const float*)d_in[2];
    const float* A_imag     = (const float*)d_in[3];
    float* out = (float*)d_out;

    dim3 grid(H_DIM);
    dim3 block(TPB);
    s4d_kernel<<<grid, block, 0, stream>>>(C, log_dt, log_A_real, A_imag, out);
}

// Round 2
// 90.134 us; speedup vs baseline: 1.1302x; 1.1302x over previous
//
#include <hip/hip_runtime.h>
#include <hip/hip_bf16.h>
#include <math.h>

// S4D kernel: K[h,l] = 2 * Re( sum_n Cm[h,n] * W[h,n]^l ),  W = exp(dtA)
//   dtA = dt * (-exp(log_A_real) + i*A_imag),  dt = exp(log_dt)
//   Cm  = Cc * (exp(dtA) - 1) / A
// H=1024, NH=N/2=32, L=4096. Output (H, L) float32.
//
// Strategy: per block (one h), 32 lanes build per-n LDS tables:
//   W (step-1 phasor), TA[j]=W^(16j), TB[j]=W^(256j)  (TB from an
//   accurately-computed W^256 so magnitude/phase error doesn't grow ~L*eps).
// Each of 256 threads owns 16 CONSECUTIVE l values (coalesced dwordx4
// stores): z = 2*Cm * TA[t&15] * TB[t>>4], then 16-step complex recurrence
// z *= W, acc[j] += Re(z). No transcendentals in the main loop.

#define H_DIM 1024
#define NH 32
#define L_DIM 4096
#define TPB 256
#define PER 16   // consecutive l per thread

__global__ __launch_bounds__(TPB) void s4d_kernel(
    const float* __restrict__ C,          // (H, NH, 2)
    const float* __restrict__ log_dt,     // (H,)
    const float* __restrict__ log_A_real, // (H, NH)
    const float* __restrict__ A_imag,     // (H, NH)
    float* __restrict__ out)              // (H, L)
{
    const int h = blockIdx.x;
    const int t = threadIdx.x;

    __shared__ float s_w[NH][2];        // W = exp(dtA)
    __shared__ float s_cm[NH][2];       // 2*Cm
    __shared__ float s_ta[NH][16][2];   // W^(16j)
    __shared__ float s_tb[NH][16][2];   // W^(256j)

    const double TWO_PI  = 6.283185307179586476925286766559;
    const double INV_2PI = 0.15915494309189533576888376337251;

    if (t < NH) {
        const int n = t;
        const float dtf = expf(log_dt[h]);
        const float arf = -expf(log_A_real[h * NH + n]); // Re(A) < 0
        const float aif = A_imag[h * NH + n];            // Im(A) >= 0
        const float are = arf * dtf;                     // Re(dtA)

        // phase step per l, reduced mod 2pi in double (once per n)
        double th = (double)aif * (double)dtf;
        th -= floor(th * INV_2PI) * TWO_PI;

        // W = exp(dtA)
        const float mw = expf(are);
        float sn, cs;
        sincosf((float)th, &sn, &cs);
        const float wr = mw * cs;
        const float wi = mw * sn;
        s_w[n][0] = wr;
        s_w[n][1] = wi;

        // Cm = Cc * (exp(dtA)-1) / A ; fold leading 2.0
        {
            const float er = wr - 1.0f;
            const float ei = wi;
            const float cr = C[(h * NH + n) * 2 + 0];
            const float ci = C[(h * NH + n) * 2 + 1];
            const float tr = cr * er - ci * ei;
            const float ti = cr * ei + ci * er;
            const float inv = 2.0f / (arf * arf + aif * aif);
            s_cm[n][0] = (tr * arf + ti * aif) * inv;
            s_cm[n][1] = (ti * arf - tr * aif) * inv;
        }

        // W^16 via 4 squarings
        float ar = wr, ai = wi;
#pragma unroll
        for (int k = 0; k < 4; ++k) {
            const float nr = ar * ar - ai * ai;
            const float ni = 2.0f * ar * ai;
            ar = nr; ai = ni;
        }
        // TA[j] = (W^16)^j
        {
            float pr = 1.0f, pi = 0.0f;
#pragma unroll
            for (int j = 0; j < 16; ++j) {
                s_ta[n][j][0] = pr;
                s_ta[n][j][1] = pi;
                const float nr = pr * ar - pi * ai;
                const float ni = pr * ai + pi * ar;
                pr = nr; pi = ni;
            }
        }
        // W^256 computed directly (accurate magnitude + phase)
        {
            const float m256 = expf(are * 256.0f);
            double p = th * 256.0;
            p -= floor(p * INV_2PI) * TWO_PI;
            float s2, c2;
            sincosf((float)p, &s2, &c2);
            const float br = m256 * c2;
            const float bi = m256 * s2;
            float pr = 1.0f, pi = 0.0f;
#pragma unroll
            for (int j = 0; j < 16; ++j) {
                s_tb[n][j][0] = pr;
                s_tb[n][j][1] = pi;
                const float nr = pr * br - pi * bi;
                const float ni = pr * bi + pi * br;
                pr = nr; pi = ni;
            }
        }
    }
    __syncthreads();

    float acc[PER];
#pragma unroll
    for (int j = 0; j < PER; ++j) acc[j] = 0.0f;

    const int ta_idx = t & 15;
    const int tb_idx = t >> 4;

    for (int n = 0; n < NH; ++n) {
        const float wr = s_w[n][0];
        const float wi = s_w[n][1];
        const float cr = s_cm[n][0];
        const float ci = s_cm[n][1];
        const float tar = s_ta[n][ta_idx][0];
        const float tai = s_ta[n][ta_idx][1];
        const float tbr = s_tb[n][tb_idx][0];
        const float tbi = s_tb[n][tb_idx][1];

        // z = 2Cm * W^(16t) = cm * ta * tb
        const float pr = tar * tbr - tai * tbi;
        const float pi = tar * tbi + tai * tbr;
        float zr = cr * pr - ci * pi;
        float zi = cr * pi + ci * pr;

#pragma unroll
        for (int j = 0; j < PER; ++j) {
            acc[j] += zr;
            const float nzr = zr * wr - zi * wi;
            const float nzi = zr * wi + zi * wr;
            zr = nzr;
            zi = nzi;
        }
    }

    float4* op = (float4*)(out + (size_t)h * L_DIM + (size_t)t * PER);
#pragma unroll
    for (int j = 0; j < PER / 4; ++j) {
        op[j] = make_float4(acc[4 * j], acc[4 * j + 1], acc[4 * j + 2], acc[4 * j + 3]);
    }
}

extern "C" void kernel_launch(void* const* d_in, const int* in_sizes, int n_in,
                              void* d_out, int out_size, void* d_ws, size_t ws_size,
                              hipStream_t stream) {
    const float* C          = (const float*)d_in[0];
    const float* log_dt     = (const float*)d_in[1];
    const float* log_A_real = (const float*)d_in[2];
    const float* A_imag     = (const float*)d_in[3];
    float* out = (float*)d_out;

    s4d_kernel<<<dim3(H_DIM), dim3(TPB), 0, stream>>>(C, log_dt, log_A_real, A_imag, out);
}

// Round 3
// 79.161 us; speedup vs baseline: 1.2869x; 1.1386x over previous
//
#include <hip/hip_runtime.h>
#include <hip/hip_bf16.h>
#include <math.h>

// S4D kernel: K[h,l] = 2 * Re( sum_n Cm[h,n] * W[h,n]^l ),  W = exp(dtA)
//   dtA = dt * (-exp(log_A_real) + i*A_imag),  dt = exp(log_dt)
//   Cm  = Cc * (exp(dtA) - 1) / A
// H=1024, NH=N/2=32, L=4096. Output (H, L) float32.
//
// Round 3:
//  - Setup fully parallel: 256 threads = 32 n x 8 slots; each slot computes
//    4 table entries DIRECTLY (mag via v_exp, phase via double-precision
//    frac-of-revolutions feeding hardware v_sin/v_cos). No serial product
//    chains, no libm sincosf, no 32-lane-only section.
//  - Main loop: 2nd-order real recurrence x_{j+1} = p*x_j + q*x_{j-1}
//    (p = 2Re(W), q = -|W|^2): 3 VALU per (n,l) instead of 5, with only a
//    single fma on the dependent chain per step.
//  - Thread t owns 16 consecutive l (coalesced dwordx4 stores);
//    z0 = 2Cm * TA[t&15] * TB[t>>4] where TA[j]=W^(16j), TB[j]=W^(256j).

#define H_DIM 1024
#define NH 32
#define L_DIM 4096
#define TPB 256
#define PER 16
#define STRIDE_F 72   // floats per n in LDS: 8 hdr + 32 TA + 32 TB (288 B, 16B-aligned)

__global__ __launch_bounds__(TPB) void s4d_kernel(
    const float* __restrict__ C,          // (H, NH, 2)
    const float* __restrict__ log_dt,     // (H,)
    const float* __restrict__ log_A_real, // (H, NH)
    const float* __restrict__ A_imag,     // (H, NH)
    float* __restrict__ out)              // (H, L)
{
    const int h = blockIdx.x;
    const int t = threadIdx.x;

    __shared__ float lds[NH * STRIDE_F];

    const double INV_2PI = 0.15915494309189533576888376337251;

    // ---------------- parallel setup ----------------
    {
        const int n = t & 31;
        const int s = t >> 5;   // slot 0..7
        const float dtf = __expf(log_dt[h]);
        const float arf = -__expf(log_A_real[h * NH + n]); // Re(A) < 0
        const float aif = A_imag[h * NH + n];              // Im(A) >= 0
        const float are = arf * dtf;                       // Re(dtA)
        const double th_rev = (double)aif * (double)dtf * INV_2PI; // phase/2pi per l

        float* base = &lds[n * STRIDE_F];

        // TA[j] = W^(16j) at base[8+2j]; TB[j] = W^(256j) at base[40+2j].
        // Slot s fills j = 2s and 2s+1 of each table.
#pragma unroll
        for (int e = 0; e < 2; ++e) {
            const int j = 2 * s + e;
            {
                const int l = 16 * j;
                const float mag = __expf(are * (float)l);
                double u = (double)l * th_rev;
                u -= floor(u);
                const float uf = (float)u;
                base[8 + 2 * j]     = mag * __builtin_amdgcn_cosf(uf);
                base[8 + 2 * j + 1] = mag * __builtin_amdgcn_sinf(uf);
            }
            {
                const int l = 256 * j;
                const float mag = __expf(are * (float)l);
                double u = (double)l * th_rev;
                u -= floor(u);
                const float uf = (float)u;
                base[40 + 2 * j]     = mag * __builtin_amdgcn_cosf(uf);
                base[40 + 2 * j + 1] = mag * __builtin_amdgcn_sinf(uf);
            }
        }

        if (s == 0) {
            // W = exp(dtA)
            const float mag = __expf(are);
            double u = th_rev - floor(th_rev);
            const float uf = (float)u;
            const float wr = mag * __builtin_amdgcn_cosf(uf);
            const float wi = mag * __builtin_amdgcn_sinf(uf);
            // Cm = Cc * (W - 1) / A, with leading 2.0 folded in
            const float cr = C[(h * NH + n) * 2 + 0];
            const float ci = C[(h * NH + n) * 2 + 1];
            const float er = wr - 1.0f;
            const float ei = wi;
            const float tr = cr * er - ci * ei;
            const float ti = cr * ei + ci * er;
            const float inv = 2.0f / (arf * arf + aif * aif);
            base[0] = wr;
            base[1] = wi;
            base[2] = (tr * arf + ti * aif) * inv;
            base[3] = (ti * arf - tr * aif) * inv;
            base[4] = wr + wr;                 // p = 2 Re(W)
            base[5] = -(wr * wr + wi * wi);    // q = -|W|^2
        }
    }
    __syncthreads();

    // ---------------- main loop ----------------
    float acc[PER];
#pragma unroll
    for (int j = 0; j < PER; ++j) acc[j] = 0.0f;

    const int ta_i = t & 15;
    const int tb_i = t >> 4;

#pragma unroll 2
    for (int n = 0; n < NH; ++n) {
        const float* base = &lds[n * STRIDE_F];
        const float4 hdr = *(const float4*)base;                   // wr wi cmr cmi
        const float2 pq  = *(const float2*)(base + 4);             // p q
        const float2 ta  = *(const float2*)(base + 8 + 2 * ta_i);
        const float2 tb  = *(const float2*)(base + 40 + 2 * tb_i);

        // z0 = cm * ta * tb  (cm already includes the 2.0 factor)
        const float pr = ta.x * tb.x - ta.y * tb.y;
        const float pi = ta.x * tb.y + ta.y * tb.x;
        const float zr = hdr.z * pr - hdr.w * pi;
        const float zi = hdr.z * pi + hdr.w * pr;

        float x0 = zr;                                  // Re(z0 W^0)
        float x1 = zr * hdr.x - zi * hdr.y;             // Re(z0 W^1)
        acc[0] += x0;
        acc[1] += x1;
        float tq = pq.y * x0;
#pragma unroll
        for (int j = 2; j < PER; ++j) {
            const float x2 = fmaf(pq.x, x1, tq);        // p*x1 + q*x0
            tq = pq.y * x1;                             // off critical path
            acc[j] += x2;
            x0 = x1;
            x1 = x2;
        }
    }

    float4* op = (float4*)(out + (size_t)h * L_DIM + (size_t)t * PER);
#pragma unroll
    for (int j = 0; j < PER / 4; ++j) {
        op[j] = make_float4(acc[4 * j], acc[4 * j + 1], acc[4 * j + 2], acc[4 * j + 3]);
    }
}

extern "C" void kernel_launch(void* const* d_in, const int* in_sizes, int n_in,
                              void* d_out, int out_size, void* d_ws, size_t ws_size,
                              hipStream_t stream) {
    const float* C          = (const float*)d_in[0];
    const float* log_dt     = (const float*)d_in[1];
    const float* log_A_real = (const float*)d_in[2];
    const float* A_imag     = (const float*)d_in[3];
    float* out = (float*)d_out;

    s4d_kernel<<<dim3(H_DIM), dim3(TPB), 0, stream>>>(C, log_dt, log_A_real, A_imag, out);
}

// Round 4
// 79.059 us; speedup vs baseline: 1.2885x; 1.0013x over previous
//
#include <hip/hip_runtime.h>
#include <hip/hip_bf16.h>
#include <math.h>

// S4D kernel: K[h,l] = 2 * Re( sum_n Cm[h,n] * W[h,n]^l ),  W = exp(dtA)
//   dtA = dt * (-exp(log_A_real) + i*A_imag),  dt = exp(log_dt)
//   Cm  = Cc * (exp(dtA) - 1) / A
// H=1024, NH=N/2=32, L=4096. Output (H, L) float32.
//
// Round 4:
//  - Occupancy 2x: grid (H, 2); each block covers 2048 l (PER=8/thread)
//    -> 8 blocks/CU = 32 waves/CU. __launch_bounds__(256,8) caps VGPR at 64.
//  - LDS traffic down: cm and W^(block l-offset) folded into TA at setup;
//    per-n header is one float4 (wr, wi, p, q); 3 ds_reads per n.
//  - Main loop: 2nd-order real recurrence x_{j+1} = p*x_j + q*x_{j-1},
//    p = 2Re(W), q = -|W|^2 = -exp(2*Re(dtA)) (computed directly).
//  - Setup fully parallel: 32 n x 8 slots; each slot computes 5 table
//    entries independently (v_exp + f64 frac-of-revolutions + v_sin/v_cos).

#define H_DIM 1024
#define NH 32
#define L_DIM 4096
#define SPLIT 2
#define L_BLK (L_DIM / SPLIT)   // 2048
#define TPB 256
#define PER 8                   // consecutive l per thread
#define NTA 32                  // TA[i] = cm * W^(off + 8i),  i in [0,32)
#define NTB 8                   // TB[j] = W^(256j),           j in [0,8)
#define STRIDE_F 84             // 4 hdr + 64 TA + 16 TB floats (336 B, 16B-aligned)

__global__ __launch_bounds__(TPB, 8) void s4d_kernel(
    const float* __restrict__ C,          // (H, NH, 2)
    const float* __restrict__ log_dt,     // (H,)
    const float* __restrict__ log_A_real, // (H, NH)
    const float* __restrict__ A_imag,     // (H, NH)
    float* __restrict__ out)              // (H, L)
{
    const int h   = blockIdx.x;
    const int off = blockIdx.y * L_BLK;
    const int t   = threadIdx.x;

    __shared__ float lds[NH * STRIDE_F];

    const double INV_2PI = 0.15915494309189533576888376337251;

    // ---------------- parallel setup ----------------
    {
        const int n = t & 31;
        const int s = t >> 5;   // slot 0..7

        const float dtf = __expf(log_dt[h]);
        const float arf = -__expf(log_A_real[h * NH + n]); // Re(A) < 0
        const float aif = A_imag[h * NH + n];              // Im(A) >= 0
        const float are = arf * dtf;                       // Re(dtA) < 0
        const double th_rev = (double)aif * (double)dtf * INV_2PI; // revs per l

        // W = exp(dtA)
        const float mw = __expf(are);
        const float u1 = (float)(th_rev - floor(th_rev));
        const float wr = mw * __builtin_amdgcn_cosf(u1);
        const float wi = mw * __builtin_amdgcn_sinf(u1);

        // cm = 2 * Cc * (W - 1) / A   (computed redundantly per slot)
        const float cr = C[(h * NH + n) * 2 + 0];
        const float ci = C[(h * NH + n) * 2 + 1];
        const float er = wr - 1.0f;
        const float ei = wi;
        const float tr = cr * er - ci * ei;
        const float ti = cr * ei + ci * er;
        const float inv = 2.0f / (arf * arf + aif * aif);
        const float cmr = (tr * arf + ti * aif) * inv;
        const float cmi = (ti * arf - tr * aif) * inv;

        float* base = &lds[n * STRIDE_F];

        // 4 TA entries: i = s + 8k ; TA[i] = cm * W^(off + 8i)
#pragma unroll
        for (int k = 0; k < 4; ++k) {
            const int i = s + 8 * k;
            const int l = off + 8 * i;
            const float mag = __expf(are * (float)l);
            double u = (double)l * th_rev;
            u -= floor(u);
            const float uf = (float)u;
            const float br = mag * __builtin_amdgcn_cosf(uf);
            const float bi = mag * __builtin_amdgcn_sinf(uf);
            base[4 + 2 * i]     = cmr * br - cmi * bi;
            base[4 + 2 * i + 1] = cmr * bi + cmi * br;
        }
        // 1 TB entry: j = s ; TB[j] = W^(256j)
        {
            const int l = 256 * s;
            const float mag = __expf(are * (float)l);
            double u = (double)l * th_rev;
            u -= floor(u);
            const float uf = (float)u;
            base[68 + 2 * s]     = mag * __builtin_amdgcn_cosf(uf);
            base[68 + 2 * s + 1] = mag * __builtin_amdgcn_sinf(uf);
        }
        if (s == 0) {
            base[0] = wr;
            base[1] = wi;
            base[2] = wr + wr;             // p = 2 Re(W)
            base[3] = -__expf(are + are);  // q = -|W|^2 = -exp(2 Re(dtA))
        }
    }
    __syncthreads();

    // ---------------- main loop ----------------
    float acc[PER];
#pragma unroll
    for (int j = 0; j < PER; ++j) acc[j] = 0.0f;

    const int ia = t & 31;   // TA index
    const int ib = t >> 5;   // TB index

#pragma unroll 4
    for (int n = 0; n < NH; ++n) {
        const float* base = &lds[n * STRIDE_F];
        const float4 hdr = *(const float4*)base;                    // wr wi p q
        const float2 ta  = *(const float2*)(base + 4 + 2 * ia);
        const float2 tb  = *(const float2*)(base + 68 + 2 * ib);

        // z0 = cm * W^(off + 8t) = TA[ia] * TB[ib]
        const float zr = ta.x * tb.x - ta.y * tb.y;
        const float zi = ta.x * tb.y + ta.y * tb.x;

        float x0 = zr;                          // Re(z0)
        float x1 = zr * hdr.x - zi * hdr.y;     // Re(z0 * W)
        acc[0] += x0;
        acc[1] += x1;
        float tq = hdr.w * x0;
#pragma unroll
        for (int j = 2; j < PER; ++j) {
            const float x2 = fmaf(hdr.z, x1, tq);   // p*x1 + q*x0
            tq = hdr.w * x1;                        // off critical path
            acc[j] += x2;
            x0 = x1;
            x1 = x2;
        }
    }

    float4* op = (float4*)(out + (size_t)h * L_DIM + off + t * PER);
#pragma unroll
    for (int j = 0; j < PER / 4; ++j) {
        op[j] = make_float4(acc[4 * j], acc[4 * j + 1], acc[4 * j + 2], acc[4 * j + 3]);
    }
}

extern "C" void kernel_launch(void* const* d_in, const int* in_sizes, int n_in,
                              void* d_out, int out_size, void* d_ws, size_t ws_size,
                              hipStream_t stream) {
    const float* C          = (const float*)d_in[0];
    const float* log_dt     = (const float*)d_in[1];
    const float* log_A_real = (const float*)d_in[2];
    const float* A_imag     = (const float*)d_in[3];
    float* out = (float*)d_out;

    s4d_kernel<<<dim3(H_DIM, SPLIT), dim3(TPB), 0, stream>>>(C, log_dt, log_A_real, A_imag, out);
}

// Round 5
// 77.903 us; speedup vs baseline: 1.3077x; 1.0148x over previous
//
#include <hip/hip_runtime.h>
#include <hip/hip_bf16.h>
#include <math.h>

// S4D kernel: K[h,l] = 2 * Re( sum_n Cm[h,n] * W[h,n]^l ),  W = exp(dtA)
//   dtA = dt * (-exp(log_A_real) + i*A_imag),  dt = exp(log_dt)
//   Cm  = Cc * (exp(dtA) - 1) / A
// H=1024, NH=N/2=32, L=4096. Output (H, L) float32.
//
// Round 5: packed dual-chain recurrence.
//  - Thread t owns l in [16t, 16t+16) as TWO 8-chains (A: +0..7, B: +8..15)
//    advanced in lockstep as float2 -> v_pk_fma_f32/v_pk_mul_f32: ~1.55x
//    fewer issue slots per (n,l), recurrence chain depth 14 -> 6.
//  - seed_B = seed_A * W^8 (W^8 per n in LDS header).
//  - 2nd-order real recurrence x_{j+1} = p*x_j + q*x_{j-1},
//    p = 2Re(W), q = -exp(2 Re(dtA)).
//  - Setup fully parallel (32 n x 8 slots), HW v_sin/v_cos on
//    frac-of-revolutions (f64 reduction), no libm, no serial chains.

#define H_DIM 1024
#define NH 32
#define L_DIM 4096
#define TPB 256
#define CHUNK 8
#define STRIDE_F 72   // 4 hdr + 2 w8 + 32 TA + 32 TB floats (288 B)

typedef float v2f __attribute__((ext_vector_type(2)));

#if defined(__has_builtin) && __has_builtin(__builtin_elementwise_fma)
#define V2FMA(a, b, c) __builtin_elementwise_fma((a), (b), (c))
#else
#define V2FMA(a, b, c) ((a) * (b) + (c))
#endif

__global__ __launch_bounds__(TPB, 4) void s4d_kernel(
    const float* __restrict__ C,          // (H, NH, 2)
    const float* __restrict__ log_dt,     // (H,)
    const float* __restrict__ log_A_real, // (H, NH)
    const float* __restrict__ A_imag,     // (H, NH)
    float* __restrict__ out)              // (H, L)
{
    const int h = blockIdx.x;
    const int t = threadIdx.x;

    __shared__ float lds[NH * STRIDE_F];

    const double INV_2PI = 0.15915494309189533576888376337251;

    // ---------------- parallel setup ----------------
    {
        const int n = t & 31;
        const int s = t >> 5;   // slot 0..7

        const float dtf = __expf(log_dt[h]);
        const float arf = -__expf(log_A_real[h * NH + n]); // Re(A) < 0
        const float aif = A_imag[h * NH + n];              // Im(A) >= 0
        const float are = arf * dtf;                       // Re(dtA) < 0
        const double th_rev = (double)aif * (double)dtf * INV_2PI; // revs per l

        // W = exp(dtA)
        const float mw = __expf(are);
        const float u1 = (float)(th_rev - floor(th_rev));
        const float wr = mw * __builtin_amdgcn_cosf(u1);
        const float wi = mw * __builtin_amdgcn_sinf(u1);

        // cm = 2 * Cc * (W - 1) / A   (redundant per slot)
        const float cr = C[(h * NH + n) * 2 + 0];
        const float ci = C[(h * NH + n) * 2 + 1];
        const float er = wr - 1.0f;
        const float ei = wi;
        const float tr = cr * er - ci * ei;
        const float ti = cr * ei + ci * er;
        const float inv = 2.0f / (arf * arf + aif * aif);
        const float cmr = (tr * arf + ti * aif) * inv;
        const float cmi = (ti * arf - tr * aif) * inv;

        float* base = &lds[n * STRIDE_F];

        // TA[i] = cm * W^(16i), i in [0,16): slot fills i = s, s+8
#pragma unroll
        for (int k = 0; k < 2; ++k) {
            const int i = s + 8 * k;
            const int l = 16 * i;
            const float mag = __expf(are * (float)l);
            double u = (double)l * th_rev;
            u -= floor(u);
            const float uf = (float)u;
            const float br = mag * __builtin_amdgcn_cosf(uf);
            const float bi = mag * __builtin_amdgcn_sinf(uf);
            base[6 + 2 * i]     = cmr * br - cmi * bi;
            base[6 + 2 * i + 1] = cmr * bi + cmi * br;
        }
        // TB[i] = W^(256i), i in [0,16): slot fills i = s, s+8
#pragma unroll
        for (int k = 0; k < 2; ++k) {
            const int i = s + 8 * k;
            const int l = 256 * i;
            const float mag = __expf(are * (float)l);
            double u = (double)l * th_rev;
            u -= floor(u);
            const float uf = (float)u;
            base[38 + 2 * i]     = mag * __builtin_amdgcn_cosf(uf);
            base[38 + 2 * i + 1] = mag * __builtin_amdgcn_sinf(uf);
        }
        if (s == 0) {
            base[0] = wr;
            base[1] = wi;
            base[2] = wr + wr;             // p = 2 Re(W)
            base[3] = -__expf(are + are);  // q = -|W|^2
            // W^8 (direct, accurate)
            const float m8 = __expf(are * 8.0f);
            double u8 = th_rev * 8.0;
            u8 -= floor(u8);
            const float uf8 = (float)u8;
            base[4] = m8 * __builtin_amdgcn_cosf(uf8);
            base[5] = m8 * __builtin_amdgcn_sinf(uf8);
        }
    }
    __syncthreads();

    // ---------------- main loop: packed dual 8-chains ----------------
    v2f acc[CHUNK];
#pragma unroll
    for (int j = 0; j < CHUNK; ++j) acc[j] = (v2f){0.0f, 0.0f};

    const int ia = t & 15;   // TA index
    const int ib = t >> 4;   // TB index

#pragma unroll 4
    for (int n = 0; n < NH; ++n) {
        const float* base = &lds[n * STRIDE_F];
        const float4 h4 = *(const float4*)base;                  // wr wi p q
        const float2 w8 = *(const float2*)(base + 4);            // W^8
        const float2 ta = *(const float2*)(base + 6 + 2 * ia);
        const float2 tb = *(const float2*)(base + 38 + 2 * ib);

        // chain A seed: zA = TA[ia]*TB[ib] = cm * W^(16t)
        const float zr  = ta.x * tb.x - ta.y * tb.y;
        const float zi  = ta.x * tb.y + ta.y * tb.x;
        // chain B seed: zB = zA * W^8
        const float zbr = zr * w8.x - zi * w8.y;
        const float zbi = zr * w8.y + zi * w8.x;

        v2f x0 = {zr, zbr};
        v2f x1 = {zr * h4.x - zi * h4.y, zbr * h4.x - zbi * h4.y};
        acc[0] += x0;
        acc[1] += x1;
        const v2f p2 = {h4.z, h4.z};
        const v2f q2 = {h4.w, h4.w};
        v2f tq = q2 * x0;
#pragma unroll
        for (int j = 2; j < CHUNK; ++j) {
            const v2f x2 = V2FMA(p2, x1, tq);
            tq = q2 * x1;                    // off critical path
            acc[j] += x2;
            x1 = x2;
        }
    }

    float4* op = (float4*)(out + (size_t)h * L_DIM + t * 16);
    op[0] = make_float4(acc[0].x, acc[1].x, acc[2].x, acc[3].x);
    op[1] = make_float4(acc[4].x, acc[5].x, acc[6].x, acc[7].x);
    op[2] = make_float4(acc[0].y, acc[1].y, acc[2].y, acc[3].y);
    op[3] = make_float4(acc[4].y, acc[5].y, acc[6].y, acc[7].y);
}

extern "C" void kernel_launch(void* const* d_in, const int* in_sizes, int n_in,
                              void* d_out, int out_size, void* d_ws, size_t ws_size,
                              hipStream_t stream) {
    const float* C          = (const float*)d_in[0];
    const float* log_dt     = (const float*)d_in[1];
    const float* log_A_real = (const float*)d_in[2];
    const float* A_imag     = (const float*)d_in[3];
    float* out = (float*)d_out;

    s4d_kernel<<<dim3(H_DIM), dim3(TPB), 0, stream>>>(C, log_dt, log_A_real, A_imag, out);
}